// Round 1
// baseline (38996.350 us; speedup 1.0000x reference)
//
#include <hip/hip_runtime.h>
#include <hip/hip_bf16.h>

// Problem constants: T=2048, B=64, I=512, H=512, fp32 throughout.
#define T_DIM 2048
#define B_DIM 64
#define I_DIM 512
#define H_DIM 512

// ---------------------------------------------------------------------------
// Kernel 1: xproj = x @ W_ih^T + (b_ih + b_hh), written into d_out in place.
//   A = x  [M=131072, K=512] row-major (K contiguous)
//   B = W_ih [N=512, K=512]  row-major (K contiguous)  -> C = A * B^T
// Tiling: 128x128 tile, BK=16, 256 threads, 8x8 micro-tile (interleaved rows
// ty+16i / cols tx+16j). LDS tiles stored k-major [16][132] (pad for banks).
// ---------------------------------------------------------------------------
__global__ __launch_bounds__(256) void xproj_gemm(
    const float* __restrict__ A, const float* __restrict__ Bw,
    const float* __restrict__ bih, const float* __restrict__ bhh,
    float* __restrict__ C)
{
    __shared__ float As[16][132];
    __shared__ float Bs[16][132];

    const int bx = blockIdx.x;
    const int bm = bx >> 2;          // 1024 m-blocks
    const int bn = bx & 3;           // 4 n-blocks (W_ih tile L2-resident)
    const int tid = threadIdx.x;
    const int tx = tid & 15;
    const int ty = tid >> 4;
    const int mbase = bm * 128;
    const int nbase = bn * 128;

    float acc[8][8] = {};

    for (int kb = 0; kb < 512; kb += 16) {
        // Stage tiles (transposed to k-major in LDS).
        #pragma unroll
        for (int s = 0; s < 2; s++) {
            const int slot = tid + s * 256;     // 512 float4 slots per tile
            const int row = slot >> 2;
            const int kv  = slot & 3;
            const float4 av = *(const float4*)(A  + (size_t)(mbase + row) * 512 + kb + kv * 4);
            const float4 bv = *(const float4*)(Bw + (size_t)(nbase + row) * 512 + kb + kv * 4);
            As[kv*4+0][row] = av.x; As[kv*4+1][row] = av.y;
            As[kv*4+2][row] = av.z; As[kv*4+3][row] = av.w;
            Bs[kv*4+0][row] = bv.x; Bs[kv*4+1][row] = bv.y;
            Bs[kv*4+2][row] = bv.z; Bs[kv*4+3][row] = bv.w;
        }
        __syncthreads();

        #pragma unroll
        for (int kk = 0; kk < 16; kk++) {
            float a[8], b[8];
            #pragma unroll
            for (int i = 0; i < 8; i++) a[i] = As[kk][ty + 16 * i];
            #pragma unroll
            for (int j = 0; j < 8; j++) b[j] = Bs[kk][tx + 16 * j];
            #pragma unroll
            for (int i = 0; i < 8; i++)
                #pragma unroll
                for (int j = 0; j < 8; j++)
                    acc[i][j] = fmaf(a[i], b[j], acc[i][j]);
        }
        __syncthreads();
    }

    #pragma unroll
    for (int j = 0; j < 8; j++) {
        const int n = nbase + tx + 16 * j;
        const float bias = bih[n] + bhh[n];
        #pragma unroll
        for (int i = 0; i < 8; i++) {
            const int m = mbase + ty + 16 * i;
            C[(size_t)m * 512 + n] = acc[i][j] + bias;
        }
    }
}

// ---------------------------------------------------------------------------
// Kernel 2: the recurrence, one workgroup per batch element (64 WGs).
// 1024 threads; thread = (column j = tid>>1, K-half = tid&1).
// W_hh row slice (256 fp32) lives in VGPRs for the whole kernel.
// h double-buffered in LDS; xproj read from (and h written back to) d_out
// in place. One __syncthreads per step.
// ---------------------------------------------------------------------------
__global__ __launch_bounds__(1024, 1) void rnn_scan(
    float* __restrict__ out,            // [T*B, H]; holds xproj on entry
    const float* __restrict__ Whh)      // [H, H] row-major
{
    __shared__ float hbuf[2][512];

    const int b    = blockIdx.x;        // batch element
    const int tid  = threadIdx.x;
    const int j    = tid >> 1;          // output column 0..511
    const int half = tid & 1;           // K-range [half*256, half*256+256)

    // Load this thread's W_hh slice into registers (fully static indices).
    float w[256];
    {
        const float4* wp = (const float4*)(Whh + (size_t)j * 512 + half * 256);
        #pragma unroll
        for (int i = 0; i < 64; i++) {
            const float4 v = wp[i];
            w[4*i+0] = v.x; w[4*i+1] = v.y; w[4*i+2] = v.z; w[4*i+3] = v.w;
        }
    }

    if (tid < 512) hbuf[0][tid] = 0.0f;   // h_0 = 0
    __syncthreads();

    for (int t = 0; t < 2048; t++) {
        const int cur = t & 1;
        float* orow = out + ((size_t)t * B_DIM + b) * 512;

        // xproj for this (t, b, j): issued early, consumed after FMA phase.
        float xp = 0.0f;
        if (half == 0) xp = orow[j];

        const float* hb = &hbuf[cur][half * 256];
        float a0 = 0.f, a1 = 0.f, a2 = 0.f, a3 = 0.f;
        #pragma unroll
        for (int i = 0; i < 64; i++) {
            const float4 hv = *(const float4*)(hb + 4 * i);  // LDS broadcast b128
            a0 = fmaf(w[4*i+0], hv.x, a0);
            a1 = fmaf(w[4*i+1], hv.y, a1);
            a2 = fmaf(w[4*i+2], hv.z, a2);
            a3 = fmaf(w[4*i+3], hv.w, a3);
        }
        float acc = (a0 + a1) + (a2 + a3);
        acc += __shfl_xor(acc, 1, 64);     // combine the two K-halves (pair lanes)

        if (half == 0) {
            const float z  = xp + acc;
            const float e  = __expf(2.0f * z);                 // robust at +-inf
            const float hn = 1.0f - __fdividef(2.0f, e + 1.0f); // tanh(z)
            hbuf[cur ^ 1][j] = hn;
            orow[j] = hn;                   // overwrite xproj with h_t
        }
        __syncthreads();
    }
}

extern "C" void kernel_launch(void* const* d_in, const int* in_sizes, int n_in,
                              void* d_out, int out_size, void* d_ws, size_t ws_size,
                              hipStream_t stream) {
    const float* x    = (const float*)d_in[0];
    const float* W_ih = (const float*)d_in[1];
    const float* W_hh = (const float*)d_in[2];
    const float* b_ih = (const float*)d_in[3];
    const float* b_hh = (const float*)d_in[4];
    float* out = (float*)d_out;

    // Phase 1: input projection (+both biases) for all timesteps -> d_out.
    xproj_gemm<<<dim3(4096), dim3(256), 0, stream>>>(x, W_ih, b_ih, b_hh, out);
    // Phase 2: sequential scan, in place on d_out.
    rnn_scan<<<dim3(64), dim3(1024), 0, stream>>>(out, W_hh);
}

// Round 2
// 25997.305 us; speedup vs baseline: 1.5000x; 1.5000x over previous
//
#include <hip/hip_runtime.h>
#include <hip/hip_bf16.h>

#define T_DIM 2048
#define B_DIM 64
#define I_DIM 512
#define H_DIM 512

// ---------------------------------------------------------------------------
// Kernel 1: xproj = x @ W_ih^T + (b_ih + b_hh) -> d_out (in place).
// ---------------------------------------------------------------------------
__global__ __launch_bounds__(256) void xproj_gemm(
    const float* __restrict__ A, const float* __restrict__ Bw,
    const float* __restrict__ bih, const float* __restrict__ bhh,
    float* __restrict__ C)
{
    __shared__ float As[16][132];
    __shared__ float Bs[16][132];

    const int bx = blockIdx.x;
    const int bm = bx >> 2;
    const int bn = bx & 3;
    const int tid = threadIdx.x;
    const int tx = tid & 15;
    const int ty = tid >> 4;
    const int mbase = bm * 128;
    const int nbase = bn * 128;

    float acc[8][8] = {};

    for (int kb = 0; kb < 512; kb += 16) {
        #pragma unroll
        for (int s = 0; s < 2; s++) {
            const int slot = tid + s * 256;
            const int row = slot >> 2;
            const int kv  = slot & 3;
            const float4 av = *(const float4*)(A  + (size_t)(mbase + row) * 512 + kb + kv * 4);
            const float4 bv = *(const float4*)(Bw + (size_t)(nbase + row) * 512 + kb + kv * 4);
            As[kv*4+0][row] = av.x; As[kv*4+1][row] = av.y;
            As[kv*4+2][row] = av.z; As[kv*4+3][row] = av.w;
            Bs[kv*4+0][row] = bv.x; Bs[kv*4+1][row] = bv.y;
            Bs[kv*4+2][row] = bv.z; Bs[kv*4+3][row] = bv.w;
        }
        __syncthreads();

        #pragma unroll
        for (int kk = 0; kk < 16; kk++) {
            float a[8], b[8];
            #pragma unroll
            for (int i = 0; i < 8; i++) a[i] = As[kk][ty + 16 * i];
            #pragma unroll
            for (int j = 0; j < 8; j++) b[j] = Bs[kk][tx + 16 * j];
            #pragma unroll
            for (int i = 0; i < 8; i++)
                #pragma unroll
                for (int j = 0; j < 8; j++)
                    acc[i][j] = fmaf(a[i], b[j], acc[i][j]);
        }
        __syncthreads();
    }

    #pragma unroll
    for (int j = 0; j < 8; j++) {
        const int n = nbase + tx + 16 * j;
        const float bias = bih[n] + bhh[n];
        #pragma unroll
        for (int i = 0; i < 8; i++) {
            const int m = mbase + ty + 16 * i;
            C[(size_t)m * 512 + n] = acc[i][j] + bias;
        }
    }
}

// ---------------------------------------------------------------------------
// Kernel 2: recurrence. 64 WGs (one per batch), 1024 threads (16 waves).
// Thread (g = tid&15, cgrp = tid>>4) handles 8 columns [cgrp*8, cgrp*8+8),
// K-window [g*32, g*32+32) for cols 0..2, interleaved k = g*4+j*64 for
// streamed cols 3..7.
//   col +0,+1 : weights in VGPRs (64 regs)          — 256 KB/CU resident
//   col +2    : weights in LDS, float2-interleaved  — 128 KB/CU resident
//   col +3..7 : streamed from L2 each step (coalesced 256B lane groups)
// h double-buffered in LDS, padded stride 36 per 32-block (bank-safe).
// 16-lane K-reduction via value-halving shfl_xor tree (8 shfl/thread).
// ---------------------------------------------------------------------------
__global__ __launch_bounds__(1024, 1) void rnn_scan(
    float* __restrict__ out,            // [T*B, H]; holds xproj on entry
    const float* __restrict__ Whh)      // [H, H] row-major
{
    extern __shared__ float smem[];
    float2* wl = (float2*)smem;          // 16 x 1024 float2 = 131072 B
    float*  hb = smem + 32768;           // 2 x 576 floats   = 4608 B

    const int b    = blockIdx.x;
    const int tid  = threadIdx.x;
    const int g    = tid & 15;
    const int cgrp = tid >> 4;
    const int cb   = cgrp << 3;
    const int kw   = g << 5;

    // column this thread owns after the reduction tree
    const int cc_own = ((g >> 1) & 1) | (((g >> 2) & 1) << 1) | (((g >> 3) & 1) << 2);
    const int xcol   = cb + cc_own;
    const bool writer = ((g & 1) == 0);
    const int waddr   = ((xcol >> 5) * 36) + (xcol & 31);

    // ---- register-resident weights: cols cb+0, cb+1, k in [kw, kw+32)
    float4 w0[8], w1[8];
    {
        const float4* p0 = (const float4*)(Whh + (size_t)(cb + 0) * 512 + kw);
        const float4* p1 = (const float4*)(Whh + (size_t)(cb + 1) * 512 + kw);
        #pragma unroll
        for (int q = 0; q < 8; q++) { w0[q] = p0[q]; w1[q] = p1[q]; }
    }
    // ---- LDS-resident weights: col cb+2, float2-interleaved [p][tid]
    {
        const float2* p2 = (const float2*)(Whh + (size_t)(cb + 2) * 512 + kw);
        #pragma unroll
        for (int p = 0; p < 16; p++) wl[p * 1024 + tid] = p2[p];
    }
    // ---- streamed base pointers: cols cb+3..cb+7, k = g*4 + j*64
    const float* ws0 = Whh + (size_t)(cb + 3) * 512 + (g << 2);
    const float* ws1 = ws0 + 512;
    const float* ws2 = ws0 + 1024;
    const float* ws3 = ws0 + 1536;
    const float* ws4 = ws0 + 2048;

    for (int i = tid; i < 1152; i += 1024) hb[i] = 0.0f;   // h0 = 0 (+pads)
    __syncthreads();

    float* outb = out + (size_t)b * H_DIM;

    for (int t = 0; t < T_DIM; t++) {
        const float* hc = hb + (t & 1) * 576;
        float*       hn = hb + ((t & 1) ^ 1) * 576;
        float* orow = outb + (size_t)t * (B_DIM * H_DIM);

        float xp = 0.0f;
        if (writer) xp = orow[xcol];    // issued early, consumed at the end

        float acc0=0.f,acc1=0.f,acc2=0.f,acc3=0.f,acc4=0.f,acc5=0.f,acc6=0.f,acc7=0.f;

        const float* hg = hc + g * 36;                       // k-window base
        const float* hsb = hc + ((g >> 3) * 36) + ((g & 7) << 2); // streamed h base

        // --- register cols (cc = 0,1)
        #pragma unroll
        for (int q = 0; q < 8; q++) {
            const float4 hv = *(const float4*)(hg + q * 4);
            acc0 = fmaf(w0[q].x, hv.x, acc0); acc0 = fmaf(w0[q].y, hv.y, acc0);
            acc0 = fmaf(w0[q].z, hv.z, acc0); acc0 = fmaf(w0[q].w, hv.w, acc0);
            acc1 = fmaf(w1[q].x, hv.x, acc1); acc1 = fmaf(w1[q].y, hv.y, acc1);
            acc1 = fmaf(w1[q].z, hv.z, acc1); acc1 = fmaf(w1[q].w, hv.w, acc1);
        }
        // --- LDS col (cc = 2)
        #pragma unroll
        for (int q = 0; q < 8; q++) {
            const float4 hv = *(const float4*)(hg + q * 4);
            const float2 a = wl[(q * 2 + 0) * 1024 + tid];
            const float2 c = wl[(q * 2 + 1) * 1024 + tid];
            acc2 = fmaf(a.x, hv.x, acc2); acc2 = fmaf(a.y, hv.y, acc2);
            acc2 = fmaf(c.x, hv.z, acc2); acc2 = fmaf(c.y, hv.w, acc2);
        }
        // --- streamed cols (cc = 3..7), k = g*4 + j*64
        #pragma unroll 4
        for (int j = 0; j < 8; j++) {
            const float4 hv = *(const float4*)(hsb + j * 72);
            const float4 v0 = *(const float4*)(ws0 + (j << 6));
            const float4 v1 = *(const float4*)(ws1 + (j << 6));
            const float4 v2 = *(const float4*)(ws2 + (j << 6));
            const float4 v3 = *(const float4*)(ws3 + (j << 6));
            const float4 v4 = *(const float4*)(ws4 + (j << 6));
            acc3 = fmaf(v0.x,hv.x,acc3); acc3 = fmaf(v0.y,hv.y,acc3);
            acc3 = fmaf(v0.z,hv.z,acc3); acc3 = fmaf(v0.w,hv.w,acc3);
            acc4 = fmaf(v1.x,hv.x,acc4); acc4 = fmaf(v1.y,hv.y,acc4);
            acc4 = fmaf(v1.z,hv.z,acc4); acc4 = fmaf(v1.w,hv.w,acc4);
            acc5 = fmaf(v2.x,hv.x,acc5); acc5 = fmaf(v2.y,hv.y,acc5);
            acc5 = fmaf(v2.z,hv.z,acc5); acc5 = fmaf(v2.w,hv.w,acc5);
            acc6 = fmaf(v3.x,hv.x,acc6); acc6 = fmaf(v3.y,hv.y,acc6);
            acc6 = fmaf(v3.z,hv.z,acc6); acc6 = fmaf(v3.w,hv.w,acc6);
            acc7 = fmaf(v4.x,hv.x,acc7); acc7 = fmaf(v4.y,hv.y,acc7);
            acc7 = fmaf(v4.z,hv.z,acc7); acc7 = fmaf(v4.w,hv.w,acc7);
        }

        // --- 16-lane reduction, value-halving tree (8 shfl + 8 add)
        float r0, r1, r2, r3;
        {
            const bool hi = (g & 8) != 0;
            const float s0 = hi ? acc0 : acc4;
            const float s1 = hi ? acc1 : acc5;
            const float s2 = hi ? acc2 : acc6;
            const float s3 = hi ? acc3 : acc7;
            r0 = (hi ? acc4 : acc0) + __shfl_xor(s0, 8, 64);
            r1 = (hi ? acc5 : acc1) + __shfl_xor(s1, 8, 64);
            r2 = (hi ? acc6 : acc2) + __shfl_xor(s2, 8, 64);
            r3 = (hi ? acc7 : acc3) + __shfl_xor(s3, 8, 64);
        }
        float u0, u1;
        {
            const bool hi = (g & 4) != 0;
            const float s0 = hi ? r0 : r2;
            const float s1 = hi ? r1 : r3;
            u0 = (hi ? r2 : r0) + __shfl_xor(s0, 4, 64);
            u1 = (hi ? r3 : r1) + __shfl_xor(s1, 4, 64);
        }
        float v;
        {
            const bool hi = (g & 2) != 0;
            const float s = hi ? u0 : u1;
            v = (hi ? u1 : u0) + __shfl_xor(s, 2, 64);
        }
        v += __shfl_xor(v, 1, 64);

        if (writer) {
            const float z  = xp + v;
            const float e  = __expf(2.0f * z);
            const float hv = 1.0f - 2.0f / (e + 1.0f);   // tanh(z)
            hn[waddr]   = hv;
            orow[xcol]  = hv;
        }
        __syncthreads();
    }
}

extern "C" void kernel_launch(void* const* d_in, const int* in_sizes, int n_in,
                              void* d_out, int out_size, void* d_ws, size_t ws_size,
                              hipStream_t stream) {
    const float* x    = (const float*)d_in[0];
    const float* W_ih = (const float*)d_in[1];
    const float* W_hh = (const float*)d_in[2];
    const float* b_ih = (const float*)d_in[3];
    const float* b_hh = (const float*)d_in[4];
    float* out = (float*)d_out;

    // Allow >64 KB dynamic LDS for the scan kernel (idempotent, non-stream op).
    static const size_t scan_lds = 131072 + 4608;   // wl + padded h double-buffer
    (void)hipFuncSetAttribute((const void*)rnn_scan,
                              hipFuncAttributeMaxDynamicSharedMemorySize,
                              (int)scan_lds);

    xproj_gemm<<<dim3(4096), dim3(256), 0, stream>>>(x, W_ih, b_ih, b_hh, out);
    rnn_scan<<<dim3(64), dim3(1024), scan_lds, stream>>>(out, W_hh);
}

// Round 3
// 11641.422 us; speedup vs baseline: 3.3498x; 2.2332x over previous
//
#include <hip/hip_runtime.h>
#include <hip/hip_bf16.h>

#define T_DIM 2048
#define B_DIM 64
#define I_DIM 512
#define H_DIM 512

typedef float f32x4 __attribute__((ext_vector_type(4)));

// ---------------------------------------------------------------------------
// Kernel 1: xproj = x @ W_ih^T + (b_ih + b_hh) -> d_out (in place).
// Also zeroes the 64 per-batch sync flags (agent-scope, visible to kernel 2).
// ---------------------------------------------------------------------------
__global__ __launch_bounds__(256) void xproj_gemm(
    const float* __restrict__ A, const float* __restrict__ Bw,
    const float* __restrict__ bih, const float* __restrict__ bhh,
    float* __restrict__ C, unsigned* __restrict__ flags)
{
    if (blockIdx.x == 0 && threadIdx.x < B_DIM)
        __hip_atomic_store(&flags[threadIdx.x], 0u,
                           __ATOMIC_RELAXED, __HIP_MEMORY_SCOPE_AGENT);

    __shared__ float As[16][132];
    __shared__ float Bs[16][132];

    const int bx = blockIdx.x;
    const int bm = bx >> 2;
    const int bn = bx & 3;
    const int tid = threadIdx.x;
    const int tx = tid & 15;
    const int ty = tid >> 4;
    const int mbase = bm * 128;
    const int nbase = bn * 128;

    float acc[8][8] = {};

    for (int kb = 0; kb < 512; kb += 16) {
        #pragma unroll
        for (int s = 0; s < 2; s++) {
            const int slot = tid + s * 256;
            const int row = slot >> 2;
            const int kv  = slot & 3;
            const float4 av = *(const float4*)(A  + (size_t)(mbase + row) * 512 + kb + kv * 4);
            const float4 bv = *(const float4*)(Bw + (size_t)(nbase + row) * 512 + kb + kv * 4);
            As[kv*4+0][row] = av.x; As[kv*4+1][row] = av.y;
            As[kv*4+2][row] = av.z; As[kv*4+3][row] = av.w;
            Bs[kv*4+0][row] = bv.x; Bs[kv*4+1][row] = bv.y;
            Bs[kv*4+2][row] = bv.z; Bs[kv*4+3][row] = bv.w;
        }
        __syncthreads();

        #pragma unroll
        for (int kk = 0; kk < 16; kk++) {
            float a[8], b[8];
            #pragma unroll
            for (int i = 0; i < 8; i++) a[i] = As[kk][ty + 16 * i];
            #pragma unroll
            for (int j = 0; j < 8; j++) b[j] = Bs[kk][tx + 16 * j];
            #pragma unroll
            for (int i = 0; i < 8; i++)
                #pragma unroll
                for (int j = 0; j < 8; j++)
                    acc[i][j] = fmaf(a[i], b[j], acc[i][j]);
        }
        __syncthreads();
    }

    #pragma unroll
    for (int j = 0; j < 8; j++) {
        const int n = nbase + tx + 16 * j;
        const float bias = bih[n] + bhh[n];
        #pragma unroll
        for (int i = 0; i < 8; i++) {
            const int m = mbase + ty + 16 * i;
            C[(size_t)m * 512 + n] = acc[i][j] + bias;
        }
    }
}

// ---------------------------------------------------------------------------
// Kernel 2: recurrence, hidden-dim split 4 ways.
// 256 WGs x 512 threads: WG = (batch b, slice s); owns cols [s*128, s*128+128).
// Thread (grp = tid>>4, g = tid&15): 4 cols {c0..c0+3}, K-window [g*32,g*32+32).
// Weights: 32 f32x4 = 128 VGPRs per thread, loaded once, pinned via empty asm.
// h: full 512 in LDS (padded 36/32 blocks). Cross-WG exchange through MALL
// (agent-scope relaxed atomics) with one cumulative flag per batch.
// ---------------------------------------------------------------------------
__global__ __launch_bounds__(512, 2) void rnn_scan(
    float* __restrict__ out,            // [T*B, H]; holds xproj on entry
    const float* __restrict__ Whh,      // [H, H] row-major
    float* __restrict__ hx,             // [2][B][H] exchange buffer (d_ws)
    unsigned* __restrict__ flags)       // [B] cumulative step counters (d_ws)
{
    __shared__ float h_lds[576];        // 16 blocks of 32 + 4 pad

    const int bid  = blockIdx.x;
    const int xcd  = bid & 7;
    const int slot = bid >> 3;
    const int b     = xcd * 8 + (slot >> 2);   // 4 slices of a batch share an XCD
    const int slice = slot & 3;
    const int tid  = threadIdx.x;
    const int grp  = tid >> 4;          // 0..31
    const int g    = tid & 15;          // K-window index
    const int c0   = slice * 128 + grp * 4;

    // ---- load 4 cols x 32 K of W_hh into registers; pin them there.
    f32x4 w[32];
    {
        const float* wp = Whh + (size_t)c0 * 512 + g * 32;
        #pragma unroll
        for (int i = 0; i < 4; i++)
            #pragma unroll
            for (int q = 0; q < 8; q++) {
                w[i * 8 + q] = *(const f32x4*)(wp + i * 512 + q * 4);
                asm volatile("" : "+v"(w[i * 8 + q]));
            }
    }

    const bool writer = (g & 3) == 0;
    const int  wcol   = c0 + ((g >> 2) & 1) + 2 * ((g >> 3) & 1);

    for (int i = tid; i < 576; i += 512) h_lds[i] = 0.0f;   // h_0 = 0
    __syncthreads();

    const float* hbp = h_lds + g * 36;

    for (int t = 0; t < T_DIM; t++) {
        float* orow = out + ((size_t)t * B_DIM + b) * H_DIM;
        float xp = 0.0f;
        if (writer) xp = orow[wcol];           // early; consumed after FMAs

        float a0 = 0.f, a1 = 0.f, a2 = 0.f, a3 = 0.f;
        #pragma unroll
        for (int q = 0; q < 8; q++) {
            const f32x4 hv = *(const f32x4*)(hbp + q * 4);
            a0 = fmaf(w[q].x,      hv.x, a0); a0 = fmaf(w[q].y,      hv.y, a0);
            a0 = fmaf(w[q].z,      hv.z, a0); a0 = fmaf(w[q].w,      hv.w, a0);
            a1 = fmaf(w[8 + q].x,  hv.x, a1); a1 = fmaf(w[8 + q].y,  hv.y, a1);
            a1 = fmaf(w[8 + q].z,  hv.z, a1); a1 = fmaf(w[8 + q].w,  hv.w, a1);
            a2 = fmaf(w[16 + q].x, hv.x, a2); a2 = fmaf(w[16 + q].y, hv.y, a2);
            a2 = fmaf(w[16 + q].z, hv.z, a2); a2 = fmaf(w[16 + q].w, hv.w, a2);
            a3 = fmaf(w[24 + q].x, hv.x, a3); a3 = fmaf(w[24 + q].y, hv.y, a3);
            a3 = fmaf(w[24 + q].z, hv.z, a3); a3 = fmaf(w[24 + q].w, hv.w, a3);
        }

        // 16-lane value-halving reduction (4 accs -> 1 col sum per subgroup)
        float v;
        {
            const bool hi = (g & 8) != 0;
            const float s0 = hi ? a0 : a2;
            const float s1 = hi ? a1 : a3;
            const float r0 = (hi ? a2 : a0) + __shfl_xor(s0, 8, 64);
            const float r1 = (hi ? a3 : a1) + __shfl_xor(s1, 8, 64);
            const bool h4 = (g & 4) != 0;
            const float s2 = h4 ? r0 : r1;
            v = (h4 ? r1 : r0) + __shfl_xor(s2, 4, 64);
            v += __shfl_xor(v, 2, 64);
            v += __shfl_xor(v, 1, 64);
        }

        float* hxb = hx + ((size_t)(t & 1) * B_DIM + b) * H_DIM;
        if (writer) {
            const float z  = xp + v;
            const float e  = __expf(2.0f * z);
            const float hv = 1.0f - 2.0f / (e + 1.0f);   // tanh(z)
            orow[wcol] = hv;
            __hip_atomic_store(&hxb[wcol], hv,
                               __ATOMIC_RELAXED, __HIP_MEMORY_SCOPE_AGENT);
        }
        __syncthreads();   // drains vmcnt -> slice stores are at MALL

        if (tid == 0) {
            __hip_atomic_fetch_add(&flags[b], 1u,
                                   __ATOMIC_RELAXED, __HIP_MEMORY_SCOPE_AGENT);
            const unsigned tgt = 4u * (unsigned)(t + 1);
            while (__hip_atomic_load(&flags[b],
                                     __ATOMIC_RELAXED, __HIP_MEMORY_SCOPE_AGENT) < tgt) {}
        }
        __syncthreads();

        const float nv = __hip_atomic_load(&hxb[tid],
                                           __ATOMIC_RELAXED, __HIP_MEMORY_SCOPE_AGENT);
        h_lds[(tid >> 5) * 36 + (tid & 31)] = nv;
        __syncthreads();
    }
}

extern "C" void kernel_launch(void* const* d_in, const int* in_sizes, int n_in,
                              void* d_out, int out_size, void* d_ws, size_t ws_size,
                              hipStream_t stream) {
    const float* x    = (const float*)d_in[0];
    const float* W_ih = (const float*)d_in[1];
    const float* W_hh = (const float*)d_in[2];
    const float* b_ih = (const float*)d_in[3];
    const float* b_hh = (const float*)d_in[4];
    float* out = (float*)d_out;

    unsigned* flags = (unsigned*)d_ws;                       // 64 * 4 B
    float*    hx    = (float*)((char*)d_ws + 1024);          // 2*64*512 * 4 B

    xproj_gemm<<<dim3(4096), dim3(256), 0, stream>>>(x, W_ih, b_ih, b_hh, out, flags);
    rnn_scan<<<dim3(256), dim3(512), 0, stream>>>(out, W_hh, hx, flags);
}

// Round 4
// 4383.455 us; speedup vs baseline: 8.8963x; 2.6558x over previous
//
#include <hip/hip_runtime.h>
#include <hip/hip_bf16.h>

#define T_DIM 2048
#define B_DIM 64
#define I_DIM 512
#define H_DIM 512

typedef float f32x4 __attribute__((ext_vector_type(4)));

union PK { unsigned long long u; float2 f; };

// ---------------------------------------------------------------------------
// Kernel 1: xproj = x @ W_ih^T + (b_ih + b_hh) -> d_out (in place).
// ---------------------------------------------------------------------------
__global__ __launch_bounds__(256) void xproj_gemm(
    const float* __restrict__ A, const float* __restrict__ Bw,
    const float* __restrict__ bih, const float* __restrict__ bhh,
    float* __restrict__ C)
{
    __shared__ float As[16][132];
    __shared__ float Bs[16][132];

    const int bx = blockIdx.x;
    const int bm = bx >> 2;
    const int bn = bx & 3;
    const int tid = threadIdx.x;
    const int tx = tid & 15;
    const int ty = tid >> 4;
    const int mbase = bm * 128;
    const int nbase = bn * 128;

    float acc[8][8] = {};

    for (int kb = 0; kb < 512; kb += 16) {
        #pragma unroll
        for (int s = 0; s < 2; s++) {
            const int slot = tid + s * 256;
            const int row = slot >> 2;
            const int kv  = slot & 3;
            const float4 av = *(const float4*)(A  + (size_t)(mbase + row) * 512 + kb + kv * 4);
            const float4 bv = *(const float4*)(Bw + (size_t)(nbase + row) * 512 + kb + kv * 4);
            As[kv*4+0][row] = av.x; As[kv*4+1][row] = av.y;
            As[kv*4+2][row] = av.z; As[kv*4+3][row] = av.w;
            Bs[kv*4+0][row] = bv.x; Bs[kv*4+1][row] = bv.y;
            Bs[kv*4+2][row] = bv.z; Bs[kv*4+3][row] = bv.w;
        }
        __syncthreads();

        #pragma unroll
        for (int kk = 0; kk < 16; kk++) {
            float a[8], b[8];
            #pragma unroll
            for (int i = 0; i < 8; i++) a[i] = As[kk][ty + 16 * i];
            #pragma unroll
            for (int j = 0; j < 8; j++) b[j] = Bs[kk][tx + 16 * j];
            #pragma unroll
            for (int i = 0; i < 8; i++)
                #pragma unroll
                for (int j = 0; j < 8; j++)
                    acc[i][j] = fmaf(a[i], b[j], acc[i][j]);
        }
        __syncthreads();
    }

    #pragma unroll
    for (int j = 0; j < 8; j++) {
        const int n = nbase + tx + 16 * j;
        const float bias = bih[n] + bhh[n];
        #pragma unroll
        for (int i = 0; i < 8; i++) {
            const int m = mbase + ty + 16 * i;
            C[(size_t)m * 512 + n] = acc[i][j] + bias;
        }
    }
}

// ---------------------------------------------------------------------------
// Kernel 2: recurrence, hidden split 4 ways. 256 WGs x 512 threads.
// WG = (batch b, slice); owns cols [slice*128, slice*128+128).
// Weights: 32 f32x4 = 128 VGPRs/thread, loaded via OPAQUE asm global_load
// (compiler cannot rematerialize -> stays register-resident).
// Exchange: {h, epoch} packed in one 8B relaxed agent-scope atomic; readers
// spin on their own slot until epoch == t+1. No flags, no flushes, one
// __syncthreads per step. Replay-safe against stale d_ws contents.
// ---------------------------------------------------------------------------
__global__ __launch_bounds__(512, 2) void rnn_scan(
    float* __restrict__ out,                    // [T*B, H]; xproj on entry
    const float* __restrict__ Whh,              // [H, H] row-major
    unsigned long long* __restrict__ hx)        // [2][B][H] packed {h,epoch}
{
    __shared__ float h_lds[2][576];             // double-buffered, 36-padded

    const int bid  = blockIdx.x;
    const int xcd  = bid & 7;
    const int slot = bid >> 3;
    const int b     = xcd * 8 + (slot >> 2);    // 4 slices of a batch: same XCD
    const int slice = slot & 3;
    const int tid  = threadIdx.x;
    const int grp  = tid >> 4;                  // 0..31
    const int g    = tid & 15;                  // K-window index
    const int c0   = slice * 128 + grp * 4;

    // ---- opaque weight load: 4 cols x 32 K -> 32 f32x4 (128 VGPRs), pinned
    f32x4 w[32];
    {
        const float* wp = Whh + (size_t)c0 * 512 + g * 32;
        #pragma unroll
        for (int i = 0; i < 4; i++)
            #pragma unroll
            for (int q = 0; q < 8; q++) {
                const float* addr = wp + i * 512 + q * 4;
                asm volatile("global_load_dwordx4 %0, %1, off"
                             : "=v"(w[i * 8 + q]) : "v"(addr));
            }
        asm volatile("s_waitcnt vmcnt(0)");
    }

    const bool writer = (g & 3) == 0;
    const int  wcol   = c0 + ((g >> 2) & 1) + 2 * ((g >> 3) & 1);
    unsigned long long* hxw = hx + (size_t)b * H_DIM + wcol;   // + parity*B*H
    unsigned long long* hxr = hx + (size_t)b * H_DIM + tid;

    for (int i = tid; i < 1152; i += 512) ((float*)h_lds)[i] = 0.0f;  // h0 = 0
    __syncthreads();

    for (int t = 0; t < T_DIM; t++) {
        const int p  = t & 1;
        const int np = p ^ 1;
        const float* hbp = h_lds[p] + g * 36;
        float* orow = out + ((size_t)t * B_DIM + b) * H_DIM;

        float xp = 0.0f;
        if (writer) xp = orow[wcol];             // early; consumed at the end

        float a0 = 0.f, a1 = 0.f, a2 = 0.f, a3 = 0.f;
        #pragma unroll
        for (int q = 0; q < 8; q++) {
            const f32x4 hv = *(const f32x4*)(hbp + q * 4);
            a0 = fmaf(w[q].x,      hv.x, a0); a0 = fmaf(w[q].y,      hv.y, a0);
            a0 = fmaf(w[q].z,      hv.z, a0); a0 = fmaf(w[q].w,      hv.w, a0);
            a1 = fmaf(w[8 + q].x,  hv.x, a1); a1 = fmaf(w[8 + q].y,  hv.y, a1);
            a1 = fmaf(w[8 + q].z,  hv.z, a1); a1 = fmaf(w[8 + q].w,  hv.w, a1);
            a2 = fmaf(w[16 + q].x, hv.x, a2); a2 = fmaf(w[16 + q].y, hv.y, a2);
            a2 = fmaf(w[16 + q].z, hv.z, a2); a2 = fmaf(w[16 + q].w, hv.w, a2);
            a3 = fmaf(w[24 + q].x, hv.x, a3); a3 = fmaf(w[24 + q].y, hv.y, a3);
            a3 = fmaf(w[24 + q].z, hv.z, a3); a3 = fmaf(w[24 + q].w, hv.w, a3);
        }

        // 16-lane value-halving reduction
        float v;
        {
            const bool hi = (g & 8) != 0;
            const float s0 = hi ? a0 : a2;
            const float s1 = hi ? a1 : a3;
            const float r0 = (hi ? a2 : a0) + __shfl_xor(s0, 8, 64);
            const float r1 = (hi ? a3 : a1) + __shfl_xor(s1, 8, 64);
            const bool h4 = (g & 4) != 0;
            const float s2 = h4 ? r0 : r1;
            v = (h4 ? r1 : r0) + __shfl_xor(s2, 4, 64);
            v += __shfl_xor(v, 2, 64);
            v += __shfl_xor(v, 1, 64);
        }

        const float tag = (float)(t + 1);
        if (writer) {
            const float z  = xp + v;
            const float e  = __expf(2.0f * z);
            const float hv = 1.0f - 2.0f / (e + 1.0f);   // tanh(z)
            orow[wcol] = hv;
            PK pk; pk.f.x = hv; pk.f.y = tag;
            __hip_atomic_store(hxw + (size_t)np * (B_DIM * H_DIM), pk.u,
                               __ATOMIC_RELAXED, __HIP_MEMORY_SCOPE_AGENT);
        }

        // spin on own slot until this step's epoch arrives
        PK rk;
        do {
            rk.u = __hip_atomic_load(hxr + (size_t)np * (B_DIM * H_DIM),
                                     __ATOMIC_RELAXED, __HIP_MEMORY_SCOPE_AGENT);
        } while (rk.f.y != tag);
        h_lds[np][(tid >> 5) * 36 + (tid & 31)] = rk.f.x;
        __syncthreads();
    }
}

extern "C" void kernel_launch(void* const* d_in, const int* in_sizes, int n_in,
                              void* d_out, int out_size, void* d_ws, size_t ws_size,
                              hipStream_t stream) {
    const float* x    = (const float*)d_in[0];
    const float* W_ih = (const float*)d_in[1];
    const float* W_hh = (const float*)d_in[2];
    const float* b_ih = (const float*)d_in[3];
    const float* b_hh = (const float*)d_in[4];
    float* out = (float*)d_out;

    unsigned long long* hx = (unsigned long long*)d_ws;   // 2*64*512*8 = 512 KB

    xproj_gemm<<<dim3(4096), dim3(256), 0, stream>>>(x, W_ih, b_ih, b_hh, out);
    rnn_scan<<<dim3(256), dim3(512), 0, stream>>>(out, W_hh, hx);
}

// Round 5
// 4336.252 us; speedup vs baseline: 8.9931x; 1.0109x over previous
//
#include <hip/hip_runtime.h>
#include <hip/hip_bf16.h>

#define T_DIM 2048
#define B_DIM 64
#define I_DIM 512
#define H_DIM 512

typedef float f32x4 __attribute__((ext_vector_type(4)));

union PK { unsigned long long u; float2 f; };

// ---------------------------------------------------------------------------
// Kernel 1: xproj = x @ W_ih^T + (b_ih + b_hh) -> d_out (in place).
// ---------------------------------------------------------------------------
__global__ __launch_bounds__(256) void xproj_gemm(
    const float* __restrict__ A, const float* __restrict__ Bw,
    const float* __restrict__ bih, const float* __restrict__ bhh,
    float* __restrict__ C)
{
    __shared__ float As[16][132];
    __shared__ float Bs[16][132];

    const int bx = blockIdx.x;
    const int bm = bx >> 2;
    const int bn = bx & 3;
    const int tid = threadIdx.x;
    const int tx = tid & 15;
    const int ty = tid >> 4;
    const int mbase = bm * 128;
    const int nbase = bn * 128;

    float acc[8][8] = {};

    for (int kb = 0; kb < 512; kb += 16) {
        #pragma unroll
        for (int s = 0; s < 2; s++) {
            const int slot = tid + s * 256;
            const int row = slot >> 2;
            const int kv  = slot & 3;
            const float4 av = *(const float4*)(A  + (size_t)(mbase + row) * 512 + kb + kv * 4);
            const float4 bv = *(const float4*)(Bw + (size_t)(nbase + row) * 512 + kb + kv * 4);
            As[kv*4+0][row] = av.x; As[kv*4+1][row] = av.y;
            As[kv*4+2][row] = av.z; As[kv*4+3][row] = av.w;
            Bs[kv*4+0][row] = bv.x; Bs[kv*4+1][row] = bv.y;
            Bs[kv*4+2][row] = bv.z; Bs[kv*4+3][row] = bv.w;
        }
        __syncthreads();

        #pragma unroll
        for (int kk = 0; kk < 16; kk++) {
            float a[8], b[8];
            #pragma unroll
            for (int i = 0; i < 8; i++) a[i] = As[kk][ty + 16 * i];
            #pragma unroll
            for (int j = 0; j < 8; j++) b[j] = Bs[kk][tx + 16 * j];
            #pragma unroll
            for (int i = 0; i < 8; i++)
                #pragma unroll
                for (int j = 0; j < 8; j++)
                    acc[i][j] = fmaf(a[i], b[j], acc[i][j]);
        }
        __syncthreads();
    }

    #pragma unroll
    for (int j = 0; j < 8; j++) {
        const int n = nbase + tx + 16 * j;
        const float bias = bih[n] + bhh[n];
        #pragma unroll
        for (int i = 0; i < 8; i++) {
            const int m = mbase + ty + 16 * i;
            C[(size_t)m * 512 + n] = acc[i][j] + bias;
        }
    }
}

// ---------------------------------------------------------------------------
// Kernel 2: recurrence, hidden split 4 ways. 256 WGs x 512 threads.
// bid = slice*64 + b  ->  all 4 slices of batch b share bid%8 (same XCD under
// round-robin dispatch; a heuristic for the fast path, never for correctness).
// Exchange: writer stores {h,tag} to a FAST slot (normal store -> writer-XCD
// L2) and a SLOW slot (agent-scope -> MALL). Readers ping-pong poll both with
// exact vmcnt counting; tag mismatch on a stale fast line just falls through.
// xproj reads are chunk-prefetched 8 steps ahead, issued post-poll so the
// pre-poll vmcnt(0) drain never waits on an HBM read.
// ---------------------------------------------------------------------------
__global__ __launch_bounds__(512, 2) void rnn_scan(
    float* __restrict__ out,                    // [T*B, H]; xproj on entry
    const float* __restrict__ Whh,              // [H, H] row-major
    unsigned long long* __restrict__ hxf,       // fast region [2][B][H]
    unsigned long long* __restrict__ hxs)       // slow region [2][B][H]
{
    __shared__ float h_lds[2][576];             // double-buffered, 36-padded

    const int bid   = blockIdx.x;
    const int b     = bid & 63;
    const int slice = bid >> 6;
    const int tid = threadIdx.x;
    const int grp = tid >> 4;                   // 0..31
    const int g   = tid & 15;                   // K-window index
    const int c0  = slice * 128 + grp * 4;

    // ---- opaque weight load: 4 cols x 32 K -> 32 f32x4 (128 VGPRs)
    f32x4 w[32];
    {
        const float* wp = Whh + (size_t)c0 * 512 + g * 32;
        #pragma unroll
        for (int i = 0; i < 4; i++)
            #pragma unroll
            for (int q = 0; q < 8; q++) {
                const float* addr = wp + i * 512 + q * 4;
                asm volatile("global_load_dwordx4 %0, %1, off"
                             : "=v"(w[i * 8 + q]) : "v"(addr));
            }
        asm volatile("s_waitcnt vmcnt(0)");
    }

    const bool writer = (g & 3) == 0;
    const int  wcol   = c0 + ((g >> 2) & 1) + 2 * ((g >> 3) & 1);

    const size_t PAR = (size_t)B_DIM * H_DIM;
    unsigned long long* fw = hxf + (size_t)b * H_DIM + wcol;
    unsigned long long* sw = hxs + (size_t)b * H_DIM + wcol;
    const unsigned long long* fr = hxf + (size_t)b * H_DIM + tid;
    const unsigned long long* sr = hxs + (size_t)b * H_DIM + tid;

    for (int i = tid; i < 1152; i += 512) ((float*)h_lds)[i] = 0.0f;  // h0 = 0
    __syncthreads();

    // initial xproj chunk: rows 0..7 for this writer's column
    float xpc[8];
    if (writer) {
        #pragma unroll
        for (int j = 0; j < 8; j++)
            xpc[j] = out[((size_t)j * B_DIM + b) * H_DIM + wcol];
    }

    for (int tb = 0; tb < T_DIM; tb += 8) {
        float xpn[8];
        #pragma unroll
        for (int j = 0; j < 8; j++) {
            const int t  = tb + j;
            const int p  = j & 1;
            const int np = p ^ 1;
            const float* hbp = h_lds[p] + g * 36;

            float a0 = 0.f, a1 = 0.f, a2 = 0.f, a3 = 0.f;
            #pragma unroll
            for (int q = 0; q < 8; q++) {
                const f32x4 hv = *(const f32x4*)(hbp + q * 4);
                a0 = fmaf(w[q].x,      hv.x, a0); a0 = fmaf(w[q].y,      hv.y, a0);
                a0 = fmaf(w[q].z,      hv.z, a0); a0 = fmaf(w[q].w,      hv.w, a0);
                a1 = fmaf(w[8 + q].x,  hv.x, a1); a1 = fmaf(w[8 + q].y,  hv.y, a1);
                a1 = fmaf(w[8 + q].z,  hv.z, a1); a1 = fmaf(w[8 + q].w,  hv.w, a1);
                a2 = fmaf(w[16 + q].x, hv.x, a2); a2 = fmaf(w[16 + q].y, hv.y, a2);
                a2 = fmaf(w[16 + q].z, hv.z, a2); a2 = fmaf(w[16 + q].w, hv.w, a2);
                a3 = fmaf(w[24 + q].x, hv.x, a3); a3 = fmaf(w[24 + q].y, hv.y, a3);
                a3 = fmaf(w[24 + q].z, hv.z, a3); a3 = fmaf(w[24 + q].w, hv.w, a3);
            }

            // 16-lane value-halving reduction
            float v;
            {
                const bool hi = (g & 8) != 0;
                const float s0 = hi ? a0 : a2;
                const float s1 = hi ? a1 : a3;
                const float r0 = (hi ? a2 : a0) + __shfl_xor(s0, 8, 64);
                const float r1 = (hi ? a3 : a1) + __shfl_xor(s1, 8, 64);
                const bool h4 = (g & 4) != 0;
                const float s2 = h4 ? r0 : r1;
                v = (h4 ? r1 : r0) + __shfl_xor(s2, 4, 64);
                v += __shfl_xor(v, 2, 64);
                v += __shfl_xor(v, 1, 64);
            }

            const float tag = (float)(t + 1);
            float hv_out = 0.f;
            if (writer) {
                const float z = xpc[j] + v;
                const float e = __expf(2.0f * z);
                hv_out = 1.0f - 2.0f / (e + 1.0f);        // tanh(z)
                PK pk; pk.f.x = hv_out; pk.f.y = tag;
                *(volatile unsigned long long*)(fw + (size_t)np * PAR) = pk.u;
                __hip_atomic_store(sw + (size_t)np * PAR, pk.u,
                                   __ATOMIC_RELAXED, __HIP_MEMORY_SCOPE_AGENT);
            }

            // drain: only fast store-acks + (once per chunk) prefetch residue
            asm volatile("s_waitcnt vmcnt(0)" ::: "memory");

            // --- dual-path ping-pong poll, exact vmcnt counting -----------
            const unsigned long long* fpoll = fr + (size_t)np * PAR;
            const unsigned long long* spoll = sr + (size_t)np * PAR;
            PK pa, pb;
            asm volatile("global_load_dwordx2 %0, %1, off sc0"
                         : "=v"(pa.u) : "v"(fpoll));
            asm volatile("global_load_dwordx2 %0, %1, off sc0 sc1"
                         : "=v"(pb.u) : "v"(spoll));
            bool have = false;
            float hval = 0.f;
            for (;;) {
                asm volatile("s_waitcnt vmcnt(1)" : "+v"(pa.u) :: "memory");
                if (!have && pa.f.y == tag) { hval = pa.f.x; have = true; }
                if (__all(have)) break;
                asm volatile("global_load_dwordx2 %0, %1, off sc0"
                             : "=v"(pa.u) : "v"(fpoll));
                asm volatile("s_waitcnt vmcnt(1)" : "+v"(pb.u) :: "memory");
                if (!have && pb.f.y == tag) { hval = pb.f.x; have = true; }
                if (__all(have)) break;
                asm volatile("global_load_dwordx2 %0, %1, off sc0 sc1"
                             : "=v"(pb.u) : "v"(spoll));
            }
            asm volatile("s_waitcnt vmcnt(0)" ::: "memory");

            // post-critical-path work: output write, next-chunk prefetch
            if (writer) {
                out[((size_t)t * B_DIM + b) * H_DIM + wcol] = hv_out;
                if (j == 4) {
                    #pragma unroll
                    for (int q = 0; q < 8; q++) {
                        int rr = tb + 8 + q; if (rr > T_DIM - 1) rr = T_DIM - 1;
                        xpn[q] = out[((size_t)rr * B_DIM + b) * H_DIM + wcol];
                    }
                }
            }

            h_lds[np][(tid >> 5) * 36 + (tid & 31)] = hval;
            __syncthreads();
        }
        if (writer) {
            #pragma unroll
            for (int q = 0; q < 8; q++) xpc[q] = xpn[q];
        }
    }
}

extern "C" void kernel_launch(void* const* d_in, const int* in_sizes, int n_in,
                              void* d_out, int out_size, void* d_ws, size_t ws_size,
                              hipStream_t stream) {
    const float* x    = (const float*)d_in[0];
    const float* W_ih = (const float*)d_in[1];
    const float* W_hh = (const float*)d_in[2];
    const float* b_ih = (const float*)d_in[3];
    const float* b_hh = (const float*)d_in[4];
    float* out = (float*)d_out;

    unsigned long long* hxf = (unsigned long long*)d_ws;             // 512 KB
    unsigned long long* hxs = (unsigned long long*)((char*)d_ws + (size_t)2 * B_DIM * H_DIM * 8);

    xproj_gemm<<<dim3(4096), dim3(256), 0, stream>>>(x, W_ih, b_ih, b_hh, out);
    rnn_scan<<<dim3(256), dim3(512), 0, stream>>>(out, W_hh, hxf, hxs);
}

// Round 11
// 3997.317 us; speedup vs baseline: 9.7556x; 1.0848x over previous
//
#include <hip/hip_runtime.h>
#include <hip/hip_bf16.h>

#define T_DIM 2048
#define B_DIM 64
#define I_DIM 512
#define H_DIM 512

typedef float f32x4 __attribute__((ext_vector_type(4)));

union PK { unsigned long long u; float2 f; };

// ---------------------------------------------------------------------------
// Kernel 1: xproj = x @ W_ih^T + (b_ih + b_hh) -> d_out (in place). (proven)
// ---------------------------------------------------------------------------
__global__ __launch_bounds__(256) void xproj_gemm(
    const float* __restrict__ A, const float* __restrict__ Bw,
    const float* __restrict__ bih, const float* __restrict__ bhh,
    float* __restrict__ C)
{
    __shared__ float As[16][132];
    __shared__ float Bs[16][132];

    const int bx = blockIdx.x;
    const int bm = bx >> 2;
    const int bn = bx & 3;
    const int tid = threadIdx.x;
    const int tx = tid & 15;
    const int ty = tid >> 4;
    const int mbase = bm * 128;
    const int nbase = bn * 128;

    float acc[8][8] = {};

    for (int kb = 0; kb < 512; kb += 16) {
        #pragma unroll
        for (int s = 0; s < 2; s++) {
            const int slot = tid + s * 256;
            const int row = slot >> 2;
            const int kv  = slot & 3;
            const float4 av = *(const float4*)(A  + (size_t)(mbase + row) * 512 + kb + kv * 4);
            const float4 bv = *(const float4*)(Bw + (size_t)(nbase + row) * 512 + kb + kv * 4);
            As[kv*4+0][row] = av.x; As[kv*4+1][row] = av.y;
            As[kv*4+2][row] = av.z; As[kv*4+3][row] = av.w;
            Bs[kv*4+0][row] = bv.x; Bs[kv*4+1][row] = bv.y;
            Bs[kv*4+2][row] = bv.z; Bs[kv*4+3][row] = bv.w;
        }
        __syncthreads();

        #pragma unroll
        for (int kk = 0; kk < 16; kk++) {
            float a[8], b[8];
            #pragma unroll
            for (int i = 0; i < 8; i++) a[i] = As[kk][ty + 16 * i];
            #pragma unroll
            for (int j = 0; j < 8; j++) b[j] = Bs[kk][tx + 16 * j];
            #pragma unroll
            for (int i = 0; i < 8; i++)
                #pragma unroll
                for (int j = 0; j < 8; j++)
                    acc[i][j] = fmaf(a[i], b[j], acc[i][j]);
        }
        __syncthreads();
    }

    #pragma unroll
    for (int j = 0; j < 8; j++) {
        const int n = nbase + tx + 16 * j;
        const float bias = bih[n] + bhh[n];
        #pragma unroll
        for (int i = 0; i < 8; i++) {
            const int m = mbase + ty + 16 * i;
            C[(size_t)m * 512 + n] = acc[i][j] + bias;
        }
    }
}

// ---------------------------------------------------------------------------
// Kernel 2: recurrence, hidden split 4 ways (fp32), round-4/5 proven skeleton.
// Deltas vs round 5 (last passing):
//  - poll = __hip_atomic_load(RELAXED, AGENT) spin loop (compiler-managed
//    waits; no manual vmcnt counting anywhere -> rounds-8/9/10 crash class
//    structurally gone; removes BOTH serial drains of round 4)
//  - own slice delivered via LDS (2 of 8 waves never poll)
//  - single agent store (round-5 dual path was dead weight)
//  - __syncthreads() kept (its implicit drain covers long-retired acks)
// Only inline asm: the pre-loop opaque weight loads (proven round 4).
// Tags parity-disjoint (slot parity (t+1)&1) -> stale data never matches;
// replay-stale d_ws values are bit-identical by determinism.
// ---------------------------------------------------------------------------
__global__ __launch_bounds__(512, 2) void rnn_scan(
    float* __restrict__ out,                    // [T*B, H]; xproj on entry
    const float* __restrict__ Whh,              // [H, H] row-major
    unsigned long long* __restrict__ hx)        // [2][B][H] packed {h,tag}
{
    __shared__ float h_lds[2][576];             // double-buffered, 36-padded

    const int bid   = blockIdx.x;
    const int b     = bid & 63;
    const int slice = bid >> 6;
    const int tid = threadIdx.x;
    const int grp = tid >> 4;                   // 0..31
    const int g   = tid & 15;                   // K-window index
    const int c0  = slice * 128 + grp * 4;

    // ---- opaque weight load: 4 cols x 32 K -> 32 f32x4 (128 VGPRs)
    f32x4 w[32];
    {
        const float* wp = Whh + (size_t)c0 * 512 + g * 32;
        #pragma unroll
        for (int i = 0; i < 4; i++)
            #pragma unroll
            for (int q = 0; q < 8; q++) {
                const float* addr = wp + i * 512 + q * 4;
                asm volatile("global_load_dwordx4 %0, %1, off"
                             : "=v"(w[i * 8 + q]) : "v"(addr));
            }
        asm volatile("s_waitcnt vmcnt(0)");
    }

    const bool writer    = (g & 3) == 0;
    const int  wcol      = c0 + ((g >> 2) & 1) + 2 * ((g >> 3) & 1);
    const bool is_reader = (tid >> 7) != slice;     // wave-uniform

    const size_t PAR = (size_t)B_DIM * H_DIM;
    unsigned long long* sw0 = hx + (size_t)b * H_DIM + wcol;   // parity 0
    unsigned long long* sw1 = sw0 + PAR;                        // parity 1
    const unsigned long long* sr0 = hx + (size_t)b * H_DIM + tid;
    const unsigned long long* sr1 = sr0 + PAR;

    const int lidx = (tid >> 5) * 36 + (tid & 31);
    const int widx = (wcol >> 5) * 36 + (wcol & 31);

    const float* xbase = out + (size_t)b * H_DIM + wcol;   // xproj col wcol
    float*       obase = out + (size_t)b * H_DIM + wcol;   // h output col

    for (int i = tid; i < 1152; i += 512) ((float*)h_lds)[i] = 0.0f;  // h0=0
    __syncthreads();

    // initial xproj chunk (rows 0..7, col wcol)
    float xpc[8];
    if (writer) {
        #pragma unroll
        for (int q = 0; q < 8; q++)
            xpc[q] = xbase[(size_t)q * PAR];
    }

    for (int tb = 0; tb < T_DIM; tb += 8) {
        float xpn[8];
        #pragma unroll
        for (int j = 0; j < 8; j++) {
            const int t  = tb + j;
            const int np = (j & 1) ^ 1;
            const float* hbp = h_lds[j & 1] + g * 36;

            float a0 = 0.f, a1 = 0.f, a2 = 0.f, a3 = 0.f;
            #pragma unroll
            for (int q = 0; q < 8; q++) {
                const f32x4 hv = *(const f32x4*)(hbp + q * 4);
                a0 = fmaf(w[q].x,      hv.x, a0); a0 = fmaf(w[q].y,      hv.y, a0);
                a0 = fmaf(w[q].z,      hv.z, a0); a0 = fmaf(w[q].w,      hv.w, a0);
                a1 = fmaf(w[8 + q].x,  hv.x, a1); a1 = fmaf(w[8 + q].y,  hv.y, a1);
                a1 = fmaf(w[8 + q].z,  hv.z, a1); a1 = fmaf(w[8 + q].w,  hv.w, a1);
                a2 = fmaf(w[16 + q].x, hv.x, a2); a2 = fmaf(w[16 + q].y, hv.y, a2);
                a2 = fmaf(w[16 + q].z, hv.z, a2); a2 = fmaf(w[16 + q].w, hv.w, a2);
                a3 = fmaf(w[24 + q].x, hv.x, a3); a3 = fmaf(w[24 + q].y, hv.y, a3);
                a3 = fmaf(w[24 + q].z, hv.z, a3); a3 = fmaf(w[24 + q].w, hv.w, a3);
            }

            // 16-lane value-halving reduction (proven)
            float v;
            {
                const bool hi = (g & 8) != 0;
                const float s0 = hi ? a0 : a2;
                const float s1 = hi ? a1 : a3;
                const float r0 = (hi ? a2 : a0) + __shfl_xor(s0, 8, 64);
                const float r1 = (hi ? a3 : a1) + __shfl_xor(s1, 8, 64);
                const bool h4 = (g & 4) != 0;
                const float s2 = h4 ? r0 : r1;
                v = (h4 ? r1 : r0) + __shfl_xor(s2, 4, 64);
                v += __shfl_xor(v, 2, 64);
                v += __shfl_xor(v, 1, 64);
            }

            const float tag = (float)(t + 1);
            if (writer) {
                const float z = xpc[j] + v;
                const float e = __expf(2.0f * z);
                const float hv_out = 1.0f - 2.0f / (e + 1.0f);   // tanh(z)
                h_lds[np][widx] = hv_out;            // own slice via LDS
                PK pk; pk.f.x = hv_out; pk.f.y = tag;
                __hip_atomic_store(np ? sw1 : sw0, pk.u,
                                   __ATOMIC_RELAXED, __HIP_MEMORY_SCOPE_AGENT);
                obase[(size_t)t * PAR] = hv_out;     // h_t -> output
            }

            if (is_reader) {                         // 6 of 8 waves poll
                const unsigned long long* poll = np ? sr1 : sr0;
                PK rk;
                do {
                    rk.u = __hip_atomic_load(poll, __ATOMIC_RELAXED,
                                             __HIP_MEMORY_SCOPE_AGENT);
                } while (rk.f.y != tag);
                h_lds[np][lidx] = rk.f.x;
            }

            if (writer && j == 4) {   // next-chunk xproj prefetch
                #pragma unroll
                for (int q = 0; q < 8; q++) {
                    int rr = tb + 8 + q; if (rr >= T_DIM) rr = T_DIM - 1;
                    xpn[q] = xbase[(size_t)rr * PAR];
                }
            }

            __syncthreads();
        }
        if (writer) {
            #pragma unroll
            for (int q = 0; q < 8; q++) xpc[q] = xpn[q];
        }
    }
}

extern "C" void kernel_launch(void* const* d_in, const int* in_sizes, int n_in,
                              void* d_out, int out_size, void* d_ws, size_t ws_size,
                              hipStream_t stream) {
    const float* x    = (const float*)d_in[0];
    const float* W_ih = (const float*)d_in[1];
    const float* W_hh = (const float*)d_in[2];
    const float* b_ih = (const float*)d_in[3];
    const float* b_hh = (const float*)d_in[4];
    float* out = (float*)d_out;

    unsigned long long* hx = (unsigned long long*)d_ws;   // 2*64*512*8 = 512 KB

    xproj_gemm<<<dim3(4096), dim3(256), 0, stream>>>(x, W_ih, b_ih, b_hh, out);
    rnn_scan<<<dim3(256), dim3(512), 0, stream>>>(out, W_hh, hx);
}